// Round 1
// baseline (1118.142 us; speedup 1.0000x reference)
//
#include <hip/hip_runtime.h>
#include <math.h>

// Problem constants (from reference): B=2, T=2048, H=8, Dk=64, D=512
#define BB 2
#define TT 2048
#define HH 8
#define DK 64
#define DD 512
#define MM (BB * TT)   // 4096 rows for the projection GEMMs (== 2T for rel_k GEMM)

// ---------------------------------------------------------------------------
// Sinusoid position encoding, computed in double to match numpy float64 path.
// pe[m, col]: col<256 -> sin((T-m) * 10000^(-2j/512)), col>=256 -> cos(...)
// ---------------------------------------------------------------------------
__global__ __launch_bounds__(256) void pe_kernel(float* __restrict__ pe) {
    int idx = blockIdx.x * 256 + threadIdx.x;      // < 2T*512 = 2097152
    int m   = idx >> 9;                            // row (0..4095)
    int col = idx & 511;
    int j   = col & 255;
    // inv_freq = 10000^(-2j/512) = exp(-2j/512 * ln(10000))
    double inv_freq = exp((double)(-2 * j) * (9.210340371976184 / 512.0));
    double ang = (double)(TT - m) * inv_freq;      // pos_seq[m] = T - m
    pe[idx] = (col < 256) ? (float)sin(ang) : (float)cos(ang);
}

// ---------------------------------------------------------------------------
// Tiled fp32 GEMM with optional bias: C[M,N] = A[M,K] @ W[K,N] + bias
// BM=64, BN=64, BK=16, 256 threads, 4x4 micro-tile per thread.
// Assumes M%64==0, N%64==0, K%16==0 (true here: 4096/512/512).
// ---------------------------------------------------------------------------
__global__ __launch_bounds__(256) void gemm_bias_kernel(
    const float* __restrict__ A, const float* __restrict__ W,
    const float* __restrict__ bias, float* __restrict__ C,
    int M, int N, int K) {
    __shared__ float As[16][68];   // [k][m], stride 68 keeps float4 reads aligned
    __shared__ float Bs[16][68];   // [k][n]

    const int tid = threadIdx.x;
    const int n0 = blockIdx.x * 64;
    const int m0 = blockIdx.y * 64;
    const int tx = tid & 15;        // n micro index
    const int ty = tid >> 4;        // m micro index

    const int ar = tid >> 2;              // A load row (0..63)
    const int ac = (tid & 3) << 2;        // A load col4 (0..12)
    const int bk = tid >> 4;              // B load k row (0..15)
    const int bc = (tid & 15) << 2;       // B load col4 (0..60)

    float acc[4][4] = {};

    for (int k0 = 0; k0 < K; k0 += 16) {
        float4 av = *(const float4*)&A[(size_t)(m0 + ar) * K + k0 + ac];
        float4 bv = *(const float4*)&W[(size_t)(k0 + bk) * N + n0 + bc];
        As[ac + 0][ar] = av.x;
        As[ac + 1][ar] = av.y;
        As[ac + 2][ar] = av.z;
        As[ac + 3][ar] = av.w;
        *(float4*)&Bs[bk][bc] = bv;
        __syncthreads();
#pragma unroll
        for (int kk = 0; kk < 16; kk++) {
            float4 a = *(const float4*)&As[kk][ty << 2];
            float4 b = *(const float4*)&Bs[kk][tx << 2];
            acc[0][0] += a.x * b.x; acc[0][1] += a.x * b.y; acc[0][2] += a.x * b.z; acc[0][3] += a.x * b.w;
            acc[1][0] += a.y * b.x; acc[1][1] += a.y * b.y; acc[1][2] += a.y * b.z; acc[1][3] += a.y * b.w;
            acc[2][0] += a.z * b.x; acc[2][1] += a.z * b.y; acc[2][2] += a.z * b.z; acc[2][3] += a.z * b.w;
            acc[3][0] += a.w * b.x; acc[3][1] += a.w * b.y; acc[3][2] += a.w * b.z; acc[3][3] += a.w * b.w;
        }
        __syncthreads();
    }

    float4 bv4 = make_float4(0.f, 0.f, 0.f, 0.f);
    if (bias) bv4 = *(const float4*)&bias[n0 + (tx << 2)];
#pragma unroll
    for (int u = 0; u < 4; u++) {
        int row = m0 + (ty << 2) + u;
        float4 o = make_float4(acc[u][0] + bv4.x, acc[u][1] + bv4.y,
                               acc[u][2] + bv4.z, acc[u][3] + bv4.w);
        *(float4*)&C[(size_t)row * N + n0 + (tx << 2)] = o;
    }
}

// ---------------------------------------------------------------------------
// Bias-fold dots:  cbk[(b*T+t)*H+h] = content_bias[h] . k[b,t,h,:]
//                  rbrk[m*H+h]      = relative_bias[h] . relk[m,h,:]
// ---------------------------------------------------------------------------
__global__ __launch_bounds__(256) void bias_dots_kernel(
    const float* __restrict__ kmat, const float* __restrict__ relk,
    const float* __restrict__ cb, const float* __restrict__ rb,
    float* __restrict__ cbk, float* __restrict__ rbrk) {
    int idx = blockIdx.x * 256 + threadIdx.x;   // 0..65535
    if (idx < BB * TT * HH) {
        int h = idx & (HH - 1);
        const float* kp  = kmat + (size_t)idx * DK;
        const float* cbp = cb + h * DK;
        float s = 0.f;
#pragma unroll
        for (int d = 0; d < DK; d++) s += cbp[d] * kp[d];
        cbk[idx] = s;
    } else {
        int i2 = idx - BB * TT * HH;            // m*H + h, m in [0,2T)
        int h = i2 & (HH - 1);
        const float* rp  = relk + (size_t)i2 * DK;
        const float* rbp = rb + h * DK;
        float s = 0.f;
#pragma unroll
        for (int d = 0; d < DK; d++) s += rbp[d] * rp[d];
        rbrk[i2] = s;
    }
}

// ---------------------------------------------------------------------------
// Flash-style relative attention (fp32, online softmax).
// One block = one (b, h, 32-query-row tile). 256 threads.
// S[i][j] = ( q[i].(k[j] + relk[m]) + cbk[j] + rbrk[m] ) * 0.125,
//   with m = T - (i0+i) + (j0+j)  (rel_shift), staged rows mm = m - mbase,
//   mbase = T - i0 - 31 + j0, so mm = 31 - i + j in [0, 62].
// ---------------------------------------------------------------------------
#define ABM 32
#define ABN 32
#define LDR 68   // row stride of Q/K/R/V tiles: multiple of 4 (float4 aligned)

__global__ __launch_bounds__(256) void attn_kernel(
    const float* __restrict__ q, const float* __restrict__ k,
    const float* __restrict__ v, const float* __restrict__ relk,
    const float* __restrict__ cbk, const float* __restrict__ rbrk,
    float* __restrict__ attn_out) {
    __shared__ float Qs[ABM][LDR];
    __shared__ float Ks[ABN][LDR];
    __shared__ float Rs[ABM + ABN][LDR];       // 63 rows used
    __shared__ float Vs[ABN][LDR];
    __shared__ float Ps[ABM][36];
    __shared__ float rowmax_s[ABM], rowsum_s[ABM], alpha_s[ABM];
    __shared__ float cbk_s[ABN], rbrk_s[ABM + ABN];

    const int tid = threadIdx.x;
    const int nI = TT / ABM;                         // 64 row tiles
    const int i0 = (blockIdx.x % nI) * ABM;
    const int h  = (blockIdx.x / nI) % HH;
    const int b  = blockIdx.x / (nI * HH);

    // base offset of head (b,h): element (t,d) at bh_off + t*512 + d
    const size_t bh_off = (size_t)b * TT * DD + (size_t)h * DK;

    // Load Q tile once (rows i0..i0+31)
    for (int f = tid; f < ABM * 16; f += 256) {
        int r = f >> 4, c = (f & 15) << 2;
        *(float4*)&Qs[r][c] = *(const float4*)&q[bh_off + (size_t)(i0 + r) * DD + c];
    }
    if (tid < ABM) { rowmax_s[tid] = -INFINITY; rowsum_s[tid] = 0.0f; }

    const int i  = tid >> 3;          // S row / O row (0..31)
    const int jg = tid & 7;           // S col group
    const int jb = jg << 2;           // S col base (0,4,..,28)
    const int dg = (tid & 7) << 3;    // O d base (0,8,..,56)
    float o[8] = {};

    for (int jt = 0; jt < TT / ABN; jt++) {
        const int j0 = jt * ABN;
        const int mbase = TT - i0 - (ABM - 1) + j0;   // in [1, 4033]
        __syncthreads();   // previous tile's AV reads done (also covers Q/init)

        // Stage K, V (rows j0..j0+31) and RelK (rows mbase..mbase+62)
        for (int f = tid; f < ABN * 16; f += 256) {
            int r = f >> 4, c = (f & 15) << 2;
            *(float4*)&Ks[r][c] = *(const float4*)&k[bh_off + (size_t)(j0 + r) * DD + c];
        }
        for (int f = tid; f < ABN * 16; f += 256) {
            int r = f >> 4, c = (f & 15) << 2;
            *(float4*)&Vs[r][c] = *(const float4*)&v[bh_off + (size_t)(j0 + r) * DD + c];
        }
        for (int f = tid; f < (ABM + ABN - 1) * 16; f += 256) {
            int r = f >> 4, c = (f & 15) << 2;
            *(float4*)&Rs[r][c] = *(const float4*)&relk[((size_t)(mbase + r) * HH + h) * DK + c];
        }
        if (tid < ABN) {
            cbk_s[tid] = cbk[((size_t)b * TT + j0 + tid) * HH + h];
        } else if (tid < ABN + ABM + ABN - 1) {
            int mm = tid - ABN;
            rbrk_s[mm] = rbrk[(size_t)(mbase + mm) * HH + h];
        }
        __syncthreads();

        // ---- S = Q.(K + R_shifted), 4 cols per thread ----
        const int mrow = (ABM - 1) - i + jb;   // 0..59
        float s[4] = {0.f, 0.f, 0.f, 0.f};
#pragma unroll
        for (int db = 0; db < 16; db++) {
            const int dd = db << 2;
            const float4 qv = *(const float4*)&Qs[i][dd];
#pragma unroll
            for (int u = 0; u < 4; u++) {
                const float4 kv = *(const float4*)&Ks[jb + u][dd];
                const float4 rv = *(const float4*)&Rs[mrow + u][dd];
                s[u] += qv.x * (kv.x + rv.x) + qv.y * (kv.y + rv.y)
                      + qv.z * (kv.z + rv.z) + qv.w * (kv.w + rv.w);
            }
        }
#pragma unroll
        for (int u = 0; u < 4; u++)
            s[u] = (s[u] + cbk_s[jb + u] + rbrk_s[mrow + u]) * 0.125f;

        // ---- online softmax (8 lanes per row, same wave) ----
        float tmax = fmaxf(fmaxf(s[0], s[1]), fmaxf(s[2], s[3]));
#pragma unroll
        for (int off = 1; off < 8; off <<= 1)
            tmax = fmaxf(tmax, __shfl_xor(tmax, off));
        float mold = rowmax_s[i];
        float mnew = fmaxf(mold, tmax);
        float p0 = expf(s[0] - mnew), p1 = expf(s[1] - mnew);
        float p2 = expf(s[2] - mnew), p3 = expf(s[3] - mnew);
        float psum = p0 + p1 + p2 + p3;
#pragma unroll
        for (int off = 1; off < 8; off <<= 1)
            psum += __shfl_xor(psum, off);
        float al = expf(mold - mnew);   // first tile: exp(-inf)=0
        if (jg == 0) {
            rowmax_s[i] = mnew;
            rowsum_s[i] = rowsum_s[i] * al + psum;
            alpha_s[i]  = al;
        }
        *(float4*)&Ps[i][jb] = make_float4(p0, p1, p2, p3);
        __syncthreads();

        // ---- O = O*alpha + P.V  (8 d-values per thread) ----
        float alr = alpha_s[i];
#pragma unroll
        for (int u = 0; u < 8; u++) o[u] *= alr;
#pragma unroll 4
        for (int jl = 0; jl < ABN; jl++) {
            float p = Ps[i][jl];
            float4 v0 = *(const float4*)&Vs[jl][dg];
            float4 v1 = *(const float4*)&Vs[jl][dg + 4];
            o[0] += p * v0.x; o[1] += p * v0.y; o[2] += p * v0.z; o[3] += p * v0.w;
            o[4] += p * v1.x; o[5] += p * v1.y; o[6] += p * v1.z; o[7] += p * v1.w;
        }
    }

    // normalize and store (same-wave read of rowsum_s is safe)
    float inv = 1.0f / rowsum_s[i];
    size_t outoff = bh_off + (size_t)(i0 + i) * DD + dg;
    *(float4*)&attn_out[outoff]     = make_float4(o[0]*inv, o[1]*inv, o[2]*inv, o[3]*inv);
    *(float4*)&attn_out[outoff + 4] = make_float4(o[4]*inv, o[5]*inv, o[6]*inv, o[7]*inv);
}

// ---------------------------------------------------------------------------
extern "C" void kernel_launch(void* const* d_in, const int* in_sizes, int n_in,
                              void* d_out, int out_size, void* d_ws, size_t ws_size,
                              hipStream_t stream) {
    const float* query  = (const float*)d_in[0];
    const float* key_in = (const float*)d_in[1];
    const float* value  = (const float*)d_in[2];
    const float* Wq = (const float*)d_in[3];
    const float* bq = (const float*)d_in[4];
    const float* Wk = (const float*)d_in[5];
    const float* bk = (const float*)d_in[6];
    const float* Wv = (const float*)d_in[7];
    const float* bv = (const float*)d_in[8];
    const float* Wr = (const float*)d_in[9];
    const float* cb = (const float*)d_in[10];
    const float* rb = (const float*)d_in[11];
    const float* Wo = (const float*)d_in[12];
    const float* bo = (const float*)d_in[13];
    float* out = (float*)d_out;

    float* ws = (float*)d_ws;
    const size_t SL = (size_t)MM * DD;        // 2097152 floats per slot
    float* qb    = ws;                        // [B,T,H,Dk]
    float* kb    = ws + SL;                   // [B,T,H,Dk]
    float* vb    = ws + 2 * SL;               // [B,T,H,Dk]
    float* relk  = ws + 3 * SL;               // [2T,H,Dk]
    float* attnv = ws + 4 * SL;               // [B,T,H*Dk]  (also reused as pe)
    float* pe    = attnv;                     // pe consumed before attnv written
    float* cbk   = ws + 5 * SL;               // [B*T*H]
    float* rbrk  = cbk + BB * TT * HH;        // [2T*H]

    const dim3 gemm_grid(DD / 64, MM / 64);   // (8, 64)

    // 1. position encodings (fp64 math, fp32 store)
    pe_kernel<<<(2 * TT * DD) / 256, 256, 0, stream>>>(pe);
    // 2. rel_k = pe @ Wr (no bias)
    gemm_bias_kernel<<<gemm_grid, 256, 0, stream>>>(pe, Wr, nullptr, relk, MM, DD, DD);
    // 3. q/k/v projections
    gemm_bias_kernel<<<gemm_grid, 256, 0, stream>>>(query,  Wq, bq, qb, MM, DD, DD);
    gemm_bias_kernel<<<gemm_grid, 256, 0, stream>>>(key_in, Wk, bk, kb, MM, DD, DD);
    gemm_bias_kernel<<<gemm_grid, 256, 0, stream>>>(value,  Wv, bv, vb, MM, DD, DD);
    // 4. bias-fold dot products
    bias_dots_kernel<<<(BB * TT * HH + 2 * TT * HH) / 256, 256, 0, stream>>>(
        kb, relk, cb, rb, cbk, rbrk);
    // 5. flash attention with rel-shift
    attn_kernel<<<BB * HH * (TT / ABM), 256, 0, stream>>>(
        qb, kb, vb, relk, cbk, rbrk, attnv);
    // 6. output projection
    gemm_bias_kernel<<<gemm_grid, 256, 0, stream>>>(attnv, Wo, bo, out, MM, DD, DD);
}

// Round 2
// 608.174 us; speedup vs baseline: 1.8385x; 1.8385x over previous
//
#include <hip/hip_runtime.h>
#include <math.h>

// Problem constants: B=2, T=2048, H=8, Dk=64, D=512
#define BB 2
#define TT 2048
#define HH 8
#define DK 64
#define DD 512
#define MM (BB * TT)

typedef unsigned int u32;
typedef unsigned short u16;
typedef __bf16 bf16x8 __attribute__((ext_vector_type(8)));
typedef float f32x4 __attribute__((ext_vector_type(4)));

union frag_u { bf16x8 f; u16 u[8]; };

// fp32 -> packed (bf16_hi << 16) | bf16_lo, RNE both. x = hi + lo to ~2^-20 rel.
__device__ __forceinline__ u32 split_pack(float x) {
    u32 u = __float_as_uint(x);
    u32 hi = (u + 0x7fffu + ((u >> 16) & 1u)) >> 16;
    float hif = __uint_as_float(hi << 16);
    float lof = x - hif;                       // exact
    u32 ul = __float_as_uint(lof);
    u32 lo = (ul + 0x7fffu + ((ul >> 16) & 1u)) >> 16;
    return (hi << 16) | lo;
}

// ---------------------------------------------------------------------------
// Sinusoid position encoding (fp64 math to match numpy float64 path).
// ---------------------------------------------------------------------------
__global__ __launch_bounds__(256) void pe_kernel(float* __restrict__ pe) {
    int idx = blockIdx.x * 256 + threadIdx.x;
    int m   = idx >> 9;
    int col = idx & 511;
    int j   = col & 255;
    double inv_freq = exp((double)(-2 * j) * (9.210340371976184 / 512.0));
    double ang = (double)(TT - m) * inv_freq;
    pe[idx] = (col < 256) ? (float)sin(ang) : (float)cos(ang);
}

// ---------------------------------------------------------------------------
// Tiled fp32 GEMM + bias. BM=BN=64, BK=16, 256 thr, 4x4 micro-tile.
// ---------------------------------------------------------------------------
__global__ __launch_bounds__(256) void gemm_bias_kernel(
    const float* __restrict__ A, const float* __restrict__ W,
    const float* __restrict__ bias, float* __restrict__ C,
    int M, int N, int K) {
    __shared__ float As[16][68];
    __shared__ float Bs[16][68];

    const int tid = threadIdx.x;
    const int n0 = blockIdx.x * 64;
    const int m0 = blockIdx.y * 64;
    const int tx = tid & 15;
    const int ty = tid >> 4;

    const int ar = tid >> 2;
    const int ac = (tid & 3) << 2;
    const int bk = tid >> 4;
    const int bc = (tid & 15) << 2;

    float acc[4][4] = {};

    for (int k0 = 0; k0 < K; k0 += 16) {
        float4 av = *(const float4*)&A[(size_t)(m0 + ar) * K + k0 + ac];
        float4 bv = *(const float4*)&W[(size_t)(k0 + bk) * N + n0 + bc];
        As[ac + 0][ar] = av.x;
        As[ac + 1][ar] = av.y;
        As[ac + 2][ar] = av.z;
        As[ac + 3][ar] = av.w;
        *(float4*)&Bs[bk][bc] = bv;
        __syncthreads();
#pragma unroll
        for (int kk = 0; kk < 16; kk++) {
            float4 a = *(const float4*)&As[kk][ty << 2];
            float4 b = *(const float4*)&Bs[kk][tx << 2];
            acc[0][0] += a.x * b.x; acc[0][1] += a.x * b.y; acc[0][2] += a.x * b.z; acc[0][3] += a.x * b.w;
            acc[1][0] += a.y * b.x; acc[1][1] += a.y * b.y; acc[1][2] += a.y * b.z; acc[1][3] += a.y * b.w;
            acc[2][0] += a.z * b.x; acc[2][1] += a.z * b.y; acc[2][2] += a.z * b.z; acc[2][3] += a.z * b.w;
            acc[3][0] += a.w * b.x; acc[3][1] += a.w * b.y; acc[3][2] += a.w * b.z; acc[3][3] += a.w * b.w;
        }
        __syncthreads();
    }

    float4 bv4 = make_float4(0.f, 0.f, 0.f, 0.f);
    if (bias) bv4 = *(const float4*)&bias[n0 + (tx << 2)];
#pragma unroll
    for (int u = 0; u < 4; u++) {
        int row = m0 + (ty << 2) + u;
        float4 o = make_float4(acc[u][0] + bv4.x, acc[u][1] + bv4.y,
                               acc[u][2] + bv4.z, acc[u][3] + bv4.w);
        *(float4*)&C[(size_t)row * N + n0 + (tx << 2)] = o;
    }
}

// ---------------------------------------------------------------------------
// Bias-fold dots, PRESCALED by 1/8 (folded softmax scale):
//   cbk[(b*T+t)*H+h] = 0.125 * content_bias[h] . k[b,t,h,:]
//   rbrk[m*H+h]      = 0.125 * relative_bias[h] . relk[m,h,:]
// ---------------------------------------------------------------------------
__global__ __launch_bounds__(256) void bias_dots_kernel(
    const float* __restrict__ kmat, const float* __restrict__ relk,
    const float* __restrict__ cb, const float* __restrict__ rb,
    float* __restrict__ cbk, float* __restrict__ rbrk) {
    int idx = blockIdx.x * 256 + threadIdx.x;
    if (idx < BB * TT * HH) {
        int h = idx & (HH - 1);
        const float* kp  = kmat + (size_t)idx * DK;
        const float* cbp = cb + h * DK;
        float s = 0.f;
#pragma unroll
        for (int d = 0; d < DK; d++) s += cbp[d] * kp[d];
        cbk[idx] = s * 0.125f;
    } else {
        int i2 = idx - BB * TT * HH;
        int h = i2 & (HH - 1);
        const float* rp  = relk + (size_t)i2 * DK;
        const float* rbp = rb + h * DK;
        float s = 0.f;
#pragma unroll
        for (int d = 0; d < DK; d++) s += rbp[d] * rp[d];
        rbrk[i2] = s * 0.125f;
    }
}

// ---------------------------------------------------------------------------
// MFMA flash attention with Transformer-XL rel-shift, bf16 hi/lo emulation.
// Block = (b, h, 64 Q rows). 256 threads = 4 waves; wave w owns rows 16w..16w+15.
// K-tile = 32 cols/iter. Rel2[i,m]=q[i].relk[m] computed per 32-wide m-chunk
// (MFMA GEMM) into a per-wave 4-slot LDS ring; gathered at m = T - i + j.
// All operands staged as packed (bf16hi<<16|bf16lo) u32 in frag-linear layout:
//   B-frag elem (k,n): region (subtile,kstep), addr = p*128 + (kquad*16+n15)*2 + (jj&1)
//   where kquad=(k>>3)&3, jj=k&7, p=jj>>1. Frag read = 4x ds_read_b64, stride 8B.
// ---------------------------------------------------------------------------
__global__ __launch_bounds__(256, 2) void attn_mfma_kernel(
    const float* __restrict__ q, const float* __restrict__ k,
    const float* __restrict__ v, const float* __restrict__ relk,
    const float* __restrict__ cbk, const float* __restrict__ rbrk,
    float* __restrict__ attn_out) {
    __shared__ __align__(16) u32 smem[16896];   // 66 KiB
    u32* Kbuf   = smem;          // [nt2][ks2] x 512
    u32* Vbuf   = smem + 2048;   // [ntd4][p4][128]
    u32* Rstage = smem + 4096;   // [nt2][ks2] x 512
    u32* Pbuf   = smem + 6144;   // 4 waves x 512
    float* ringf = (float*)(smem + 8192);  // 4 waves x 4 slots x 16 x 34

    const int tid  = threadIdx.x;
    const int w    = tid >> 6;
    const int lane = tid & 63;
    const int quad = lane >> 4;
    const int c    = lane & 15;
    const int bx  = blockIdx.x;
    const int it0 = bx & 31;
    const int h   = (bx >> 5) & 7;
    const int b   = bx >> 8;
    const int i0  = it0 * 64;
    const size_t bh_off = (size_t)b * TT * DD + (size_t)h * DK;

    // ---- Q A-frags (hi/lo), prescaled by 1/8; rows = i0+16w+c, k = s*32+quad*8+j
    frag_u qh[2], ql[2];
    {
        const float* qrow = q + bh_off + (size_t)(i0 + 16 * w + c) * DD;
#pragma unroll
        for (int s = 0; s < 2; s++) {
            int d0 = s * 32 + quad * 8;
            float4 a  = *(const float4*)(qrow + d0);
            float4 b4 = *(const float4*)(qrow + d0 + 4);
            float xs[8] = {a.x, a.y, a.z, a.w, b4.x, b4.y, b4.z, b4.w};
#pragma unroll
            for (int j2 = 0; j2 < 8; j2++) {
                u32 pk = split_pack(xs[j2] * 0.125f);
                qh[s].u[j2] = (u16)(pk >> 16);
                ql[s].u[j2] = (u16)(pk & 0xffffu);
            }
        }
    }

    // ---- staging helpers (256 threads: row = tid>>3, f = tid&7 -> 8 dims) ----
    auto stage_KR = [&](const float* src_base, size_t row_stride, u32* dst) {
        int r = tid >> 3, f = tid & 7;
        const float* src = src_base + (size_t)r * row_stride + f * 8;
        float4 a  = *(const float4*)(src);
        float4 b4 = *(const float4*)(src + 4);
        int nt = r >> 4, rc = r & 15;
#pragma unroll
        for (int half = 0; half < 2; half++) {
            float4 vv = half ? b4 : a;
            int d4 = f * 8 + half * 4;
            int s = d4 >> 5, qd = (d4 >> 3) & 3, p0 = (d4 & 7) >> 1;
            u32* base = dst + ((nt * 2 + s) * 4 + p0) * 128 + (qd * 16 + rc) * 2;
            base[0]   = split_pack(vv.x);
            base[1]   = split_pack(vv.y);
            base[128] = split_pack(vv.z);
            base[129] = split_pack(vv.w);
        }
    };
    auto stage_V = [&](int j0) {
        int j = tid >> 3, f = tid & 7;
        const float* src = v + bh_off + (size_t)(j0 + j) * DD + f * 8;
        float4 a  = *(const float4*)(src);
        float4 b4 = *(const float4*)(src + 4);
        float xs[8] = {a.x, a.y, a.z, a.w, b4.x, b4.y, b4.z, b4.w};
        int qj = j >> 3, jj = j & 7, p = jj >> 1, o1 = jj & 1;
#pragma unroll
        for (int e = 0; e < 8; e++) {
            int d = f * 8 + e;
            int ntd = d >> 4, dc = d & 15;
            Vbuf[(ntd * 4 + p) * 128 + (qj * 16 + dc) * 2 + o1] = split_pack(xs[e]);
        }
    };
    auto read_pair = [&](const u32* base, frag_u& fh, frag_u& fl) {
        uint2 r0 = *(const uint2*)(base + lane * 2);
        uint2 r1 = *(const uint2*)(base + 128 + lane * 2);
        uint2 r2 = *(const uint2*)(base + 256 + lane * 2);
        uint2 r3 = *(const uint2*)(base + 384 + lane * 2);
        u32 pk[8] = {r0.x, r0.y, r1.x, r1.y, r2.x, r2.y, r3.x, r3.y};
#pragma unroll
        for (int j2 = 0; j2 < 8; j2++) {
            fh.u[j2] = (u16)(pk[j2] >> 16);
            fl.u[j2] = (u16)(pk[j2] & 0xffffu);
        }
    };
    // Rel2 for one 32-wide m-chunk into this wave's ring slot (rbrk folded in).
    auto produce_rel2 = [&](int cidx) {
        float* ringw = ringf + w * 2176 + (cidx & 3) * 544;
#pragma unroll
        for (int nt = 0; nt < 2; nt++) {
            f32x4 rc = {0.f, 0.f, 0.f, 0.f};
#pragma unroll
            for (int s = 0; s < 2; s++) {
                frag_u bh_, bl_;
                read_pair(Rstage + (nt * 2 + s) * 512, bh_, bl_);
                rc = __builtin_amdgcn_mfma_f32_16x16x32_bf16(qh[s].f, bh_.f, rc, 0, 0, 0);
                rc = __builtin_amdgcn_mfma_f32_16x16x32_bf16(qh[s].f, bl_.f, rc, 0, 0, 0);
                rc = __builtin_amdgcn_mfma_f32_16x16x32_bf16(ql[s].f, bh_.f, rc, 0, 0, 0);
            }
            int mpos = nt * 16 + c;
            float rbv = rbrk[(size_t)(cidx * 32 + mpos) * HH + h];
#pragma unroll
            for (int r = 0; r < 4; r++) {
                int row16 = quad * 4 + r;
                ringw[row16 * 34 + mpos] = rc[r] + rbv;
            }
        }
    };

    const int k0c = (TT - i0 - 63) >> 5;   // first m-chunk; (TT-i0-63) % 32 == 1

    // ---- prologue: chunks k0c, k0c+1 ----
    stage_KR(relk + ((size_t)(k0c * 32) * HH + h) * DK, (size_t)HH * DK, Rstage);
    __syncthreads();
    produce_rel2(k0c);
    __syncthreads();
    stage_KR(relk + ((size_t)((k0c + 1) * 32) * HH + h) * DK, (size_t)HH * DK, Rstage);
    __syncthreads();
    produce_rel2(k0c + 1);

    float m_run[4], l_run[4];
    f32x4 o[4];
#pragma unroll
    for (int r = 0; r < 4; r++) { m_run[r] = -INFINITY; l_run[r] = 0.f; }
#pragma unroll
    for (int nt = 0; nt < 4; nt++) o[nt] = (f32x4){0.f, 0.f, 0.f, 0.f};

    for (int jt = 0; jt < TT / 32; jt++) {
        const int j0 = jt * 32;
        __syncthreads();   // previous iteration's K/V/Rstage reads done
        stage_KR(k + bh_off + (size_t)j0 * DD, (size_t)DD, Kbuf);
        stage_V(j0);
        stage_KR(relk + ((size_t)((k0c + jt + 2) * 32) * HH + h) * DK, (size_t)HH * DK, Rstage);
        __syncthreads();
        produce_rel2(k0c + jt + 2);

        // ---- S = (QK + Rel2_gather + cbk) (all prescaled by 1/8) ----
        float sv[2][4];
#pragma unroll
        for (int nt = 0; nt < 2; nt++) {
            f32x4 sc = {0.f, 0.f, 0.f, 0.f};
#pragma unroll
            for (int s = 0; s < 2; s++) {
                frag_u bh_, bl_;
                read_pair(Kbuf + (nt * 2 + s) * 512, bh_, bl_);
                sc = __builtin_amdgcn_mfma_f32_16x16x32_bf16(qh[s].f, bh_.f, sc, 0, 0, 0);
                sc = __builtin_amdgcn_mfma_f32_16x16x32_bf16(qh[s].f, bl_.f, sc, 0, 0, 0);
                sc = __builtin_amdgcn_mfma_f32_16x16x32_bf16(ql[s].f, bh_.f, sc, 0, 0, 0);
            }
            int j_abs = j0 + nt * 16 + c;
            float cbv = cbk[((size_t)b * TT + j_abs) * HH + h];
#pragma unroll
            for (int r = 0; r < 4; r++) {
                int row16 = quad * 4 + r;
                int m_abs = TT - (i0 + 16 * w + row16) + j_abs;
                float rel = ringf[w * 2176 + ((m_abs >> 5) & 3) * 544
                                  + row16 * 34 + (m_abs & 31)];
                sv[nt][r] = sc[r] + rel + cbv;
            }
        }

        // ---- online softmax (row = 16 lanes of a quad) + P write ----
#pragma unroll
        for (int r = 0; r < 4; r++) {
            float tm = fmaxf(sv[0][r], sv[1][r]);
#pragma unroll
            for (int off = 1; off < 16; off <<= 1) tm = fmaxf(tm, __shfl_xor(tm, off));
            float mnew = fmaxf(m_run[r], tm);
            float al = __expf(m_run[r] - mnew);
            float p0 = __expf(sv[0][r] - mnew);
            float p1 = __expf(sv[1][r] - mnew);
            float ps = p0 + p1;
#pragma unroll
            for (int off = 1; off < 16; off <<= 1) ps += __shfl_xor(ps, off);
            l_run[r] = l_run[r] * al + ps;
            m_run[r] = mnew;
#pragma unroll
            for (int nt = 0; nt < 4; nt++) o[nt][r] *= al;
            int row16 = quad * 4 + r;
            u32* pb = Pbuf + w * 512;
            int jl = c;                       // nt=0 col
            pb[((jl & 7) >> 1) * 128 + ((jl >> 3) * 16 + row16) * 2 + (jl & 1)] = split_pack(p0);
            jl = 16 + c;                      // nt=1 col
            pb[((jl & 7) >> 1) * 128 + ((jl >> 3) * 16 + row16) * 2 + (jl & 1)] = split_pack(p1);
        }

        // ---- O += P @ V (hi/lo) ----
        frag_u ph, pl;
        read_pair(Pbuf + w * 512, ph, pl);
#pragma unroll
        for (int nt = 0; nt < 4; nt++) {
            frag_u vh_, vl_;
            read_pair(Vbuf + nt * 512, vh_, vl_);
            o[nt] = __builtin_amdgcn_mfma_f32_16x16x32_bf16(ph.f, vh_.f, o[nt], 0, 0, 0);
            o[nt] = __builtin_amdgcn_mfma_f32_16x16x32_bf16(ph.f, vl_.f, o[nt], 0, 0, 0);
            o[nt] = __builtin_amdgcn_mfma_f32_16x16x32_bf16(pl.f, vh_.f, o[nt], 0, 0, 0);
        }
    }

    // ---- epilogue: normalize, store [B,T,H*Dk] ----
#pragma unroll
    for (int nt = 0; nt < 4; nt++) {
#pragma unroll
        for (int r = 0; r < 4; r++) {
            int row16 = quad * 4 + r;
            int i_abs = i0 + 16 * w + row16;
            attn_out[((size_t)b * TT + i_abs) * DD + h * DK + nt * 16 + c] =
                o[nt][r] / l_run[r];
        }
    }
}

// ---------------------------------------------------------------------------
extern "C" void kernel_launch(void* const* d_in, const int* in_sizes, int n_in,
                              void* d_out, int out_size, void* d_ws, size_t ws_size,
                              hipStream_t stream) {
    const float* query  = (const float*)d_in[0];
    const float* key_in = (const float*)d_in[1];
    const float* value  = (const float*)d_in[2];
    const float* Wq = (const float*)d_in[3];
    const float* bq = (const float*)d_in[4];
    const float* Wk = (const float*)d_in[5];
    const float* bk = (const float*)d_in[6];
    const float* Wv = (const float*)d_in[7];
    const float* bv = (const float*)d_in[8];
    const float* Wr = (const float*)d_in[9];
    const float* cb = (const float*)d_in[10];
    const float* rb = (const float*)d_in[11];
    const float* Wo = (const float*)d_in[12];
    const float* bo = (const float*)d_in[13];
    float* out = (float*)d_out;

    float* ws = (float*)d_ws;
    const size_t SL = (size_t)MM * DD;
    float* qb    = ws;
    float* kb    = ws + SL;
    float* vb    = ws + 2 * SL;
    float* relk  = ws + 3 * SL;
    float* attnv = ws + 4 * SL;
    float* pe    = attnv;            // pe consumed before attnv written
    float* cbk   = ws + 5 * SL;
    float* rbrk  = cbk + BB * TT * HH;

    const dim3 gemm_grid(DD / 64, MM / 64);

    pe_kernel<<<(2 * TT * DD) / 256, 256, 0, stream>>>(pe);
    gemm_bias_kernel<<<gemm_grid, 256, 0, stream>>>(pe, Wr, nullptr, relk, MM, DD, DD);
    gemm_bias_kernel<<<gemm_grid, 256, 0, stream>>>(query,  Wq, bq, qb, MM, DD, DD);
    gemm_bias_kernel<<<gemm_grid, 256, 0, stream>>>(key_in, Wk, bk, kb, MM, DD, DD);
    gemm_bias_kernel<<<gemm_grid, 256, 0, stream>>>(value,  Wv, bv, vb, MM, DD, DD);
    bias_dots_kernel<<<(BB * TT * HH + 2 * TT * HH) / 256, 256, 0, stream>>>(
        kb, relk, cb, rb, cbk, rbrk);
    attn_mfma_kernel<<<BB * HH * (TT / 64), 256, 0, stream>>>(
        qb, kb, vb, relk, cbk, rbrk, attnv);
    gemm_bias_kernel<<<gemm_grid, 256, 0, stream>>>(attnv, Wo, bo, out, MM, DD, DD);
}

// Round 3
// 523.499 us; speedup vs baseline: 2.1359x; 1.1617x over previous
//
#include <hip/hip_runtime.h>
#include <math.h>

// Problem constants: B=2, T=2048, H=8, Dk=64, D=512
#define BB 2
#define TT 2048
#define HH 8
#define DK 64
#define DD 512
#define MM (BB * TT)

typedef unsigned int u32;
typedef unsigned short u16;
typedef __bf16 bf16x8 __attribute__((ext_vector_type(8)));
typedef float f32x4 __attribute__((ext_vector_type(4)));

union frag_u { bf16x8 f; u16 u[8]; };

// fp32 -> bf16 hi + bf16 lo (RNE both); x ~= hi + lo to ~2^-20 rel.
__device__ __forceinline__ void split2(float x, u16& h, u16& l) {
    u32 u = __float_as_uint(x);
    u32 hi = (u + 0x7fffu + ((u >> 16) & 1u)) >> 16;
    float hif = __uint_as_float(hi << 16);
    float lof = x - hif;                       // exact
    u32 ul = __float_as_uint(lof);
    u32 lo = (ul + 0x7fffu + ((ul >> 16) & 1u)) >> 16;
    h = (u16)hi; l = (u16)lo;
}
__device__ __forceinline__ u32 split_pack(float x) {
    u16 h, l; split2(x, h, l);
    return ((u32)h << 16) | (u32)l;
}

// ---------------------------------------------------------------------------
// Sinusoid position encoding (fp64 math to match numpy float64 path).
// ---------------------------------------------------------------------------
__global__ __launch_bounds__(256) void pe_kernel(float* __restrict__ pe) {
    int idx = blockIdx.x * 256 + threadIdx.x;
    int m   = idx >> 9;
    int col = idx & 511;
    int j   = col & 255;
    double inv_freq = exp((double)(-2 * j) * (9.210340371976184 / 512.0));
    double ang = (double)(TT - m) * inv_freq;
    pe[idx] = (col < 256) ? (float)sin(ang) : (float)cos(ang);
}

// ---------------------------------------------------------------------------
// Tiled fp32 GEMM + bias. BM=BN=64, BK=16, 256 thr, 4x4 micro-tile.
// ---------------------------------------------------------------------------
__global__ __launch_bounds__(256) void gemm_bias_kernel(
    const float* __restrict__ A, const float* __restrict__ W,
    const float* __restrict__ bias, float* __restrict__ C,
    int M, int N, int K) {
    __shared__ float As[16][68];
    __shared__ float Bs[16][68];

    const int tid = threadIdx.x;
    const int n0 = blockIdx.x * 64;
    const int m0 = blockIdx.y * 64;
    const int tx = tid & 15;
    const int ty = tid >> 4;

    const int ar = tid >> 2;
    const int ac = (tid & 3) << 2;
    const int bk = tid >> 4;
    const int bc = (tid & 15) << 2;

    float acc[4][4] = {};

    for (int k0 = 0; k0 < K; k0 += 16) {
        float4 av = *(const float4*)&A[(size_t)(m0 + ar) * K + k0 + ac];
        float4 bv = *(const float4*)&W[(size_t)(k0 + bk) * N + n0 + bc];
        As[ac + 0][ar] = av.x;
        As[ac + 1][ar] = av.y;
        As[ac + 2][ar] = av.z;
        As[ac + 3][ar] = av.w;
        *(float4*)&Bs[bk][bc] = bv;
        __syncthreads();
#pragma unroll
        for (int kk = 0; kk < 16; kk++) {
            float4 a = *(const float4*)&As[kk][ty << 2];
            float4 b = *(const float4*)&Bs[kk][tx << 2];
            acc[0][0] += a.x * b.x; acc[0][1] += a.x * b.y; acc[0][2] += a.x * b.z; acc[0][3] += a.x * b.w;
            acc[1][0] += a.y * b.x; acc[1][1] += a.y * b.y; acc[1][2] += a.y * b.z; acc[1][3] += a.y * b.w;
            acc[2][0] += a.z * b.x; acc[2][1] += a.z * b.y; acc[2][2] += a.z * b.z; acc[2][3] += a.z * b.w;
            acc[3][0] += a.w * b.x; acc[3][1] += a.w * b.y; acc[3][2] += a.w * b.z; acc[3][3] += a.w * b.w;
        }
        __syncthreads();
    }

    float4 bv4 = make_float4(0.f, 0.f, 0.f, 0.f);
    if (bias) bv4 = *(const float4*)&bias[n0 + (tx << 2)];
#pragma unroll
    for (int u = 0; u < 4; u++) {
        int row = m0 + (ty << 2) + u;
        float4 o = make_float4(acc[u][0] + bv4.x, acc[u][1] + bv4.y,
                               acc[u][2] + bv4.z, acc[u][3] + bv4.w);
        *(float4*)&C[(size_t)row * N + n0 + (tx << 2)] = o;
    }
}

// ---------------------------------------------------------------------------
// Bias-fold dots, PRESCALED by 1/8, stored HEAD-MAJOR for coalesced gather:
//   cbk[(h*B + b)*T + t]  = 0.125 * content_bias[h] . k[b,t,h,:]
//   rbrk[h*2T + m]        = 0.125 * relative_bias[h] . relk[m,h,:]
// ---------------------------------------------------------------------------
__global__ __launch_bounds__(256) void bias_dots_kernel(
    const float* __restrict__ kmat, const float* __restrict__ relk,
    const float* __restrict__ cb, const float* __restrict__ rb,
    float* __restrict__ cbk, float* __restrict__ rbrk) {
    int idx = blockIdx.x * 256 + threadIdx.x;
    if (idx < BB * TT * HH) {
        int h = idx & (HH - 1);
        int bt = idx >> 3;                 // b*T + t
        int b = bt >> 11, t = bt & (TT - 1);
        const float* kp  = kmat + (size_t)idx * DK;
        const float* cbp = cb + h * DK;
        float s = 0.f;
#pragma unroll
        for (int d = 0; d < DK; d++) s += cbp[d] * kp[d];
        cbk[((size_t)h * BB + b) * TT + t] = s * 0.125f;
    } else {
        int i2 = idx - BB * TT * HH;       // m*H + h
        int h = i2 & (HH - 1);
        int m = i2 >> 3;
        const float* rp  = relk + (size_t)i2 * DK;
        const float* rbp = rb + h * DK;
        float s = 0.f;
#pragma unroll
        for (int d = 0; d < DK; d++) s += rbp[d] * rp[d];
        rbrk[(size_t)h * (2 * TT) + m] = s * 0.125f;
    }
}

// ---------------------------------------------------------------------------
// MFMA flash attention with Transformer-XL rel-shift, bf16 hi/lo emulation.
// Block = (b, h, 64 Q rows), 256 thr = 4 waves; wave w owns rows 16w..16w+15.
//
// LDS: hi and lo stored in SEPARATE u16 regions; a frag = one 16B granule
// read directly as bf16x8 (no unpack). Granule swizzles chosen so both the
// staging writes (thread = row-major) and frag reads (lane = kquad-major)
// hit all 8 bank-groups per 8-lane phase — conflict-free both sides:
//   K/R: g(nt,n,s,kq) = nt*128 + n*8 + ((4s+kq+5n)&7)    [2 nt x 2 s x 32 rows]
//   V:   g(ntd,n,kq)  = ntd*80 + n*5 + kq                [pad stride 5]
// ---------------------------------------------------------------------------
__global__ __launch_bounds__(256, 2) void attn_mfma_kernel(
    const float* __restrict__ q, const float* __restrict__ k,
    const float* __restrict__ v, const float* __restrict__ relk,
    const float* __restrict__ cbk, const float* __restrict__ rbrk,
    float* __restrict__ attn_out) {
    __shared__ __align__(16) unsigned char smem[71168];
    u16* Khi = (u16*)smem;               // 2048 u16 = 4 KB
    u16* Klo = Khi + 2048;
    u16* Rhi = Klo + 2048;
    u16* Rlo = Rhi + 2048;
    u16* Vhi = Rlo + 2048;               // 2560 u16 = 5 KB
    u16* Vlo = Vhi + 2560;
    u32* Pbuf = (u32*)(Vlo + 2560);      // 4 waves x 544 u32 (16 rows x 34)
    float* ringf = (float*)(Pbuf + 4 * 544);  // 4 waves x 4 slots x 16 x 35

    const int tid  = threadIdx.x;
    const int w    = tid >> 6;
    const int lane = tid & 63;
    const int quad = lane >> 4;
    const int c    = lane & 15;
    const int bx  = blockIdx.x;
    const int it0 = bx & 31;
    const int h   = (bx >> 5) & 7;
    const int b   = bx >> 8;
    const int i0  = it0 * 64;
    const size_t bh_off = (size_t)b * TT * DD + (size_t)h * DK;

    // ---- Q A-frags (hi/lo), prescaled by 1/8; row = i0+16w+c, k = 32s+8quad+j
    frag_u qh[2], ql[2];
    {
        const float* qrow = q + bh_off + (size_t)(i0 + 16 * w + c) * DD;
#pragma unroll
        for (int s = 0; s < 2; s++) {
            int d0 = s * 32 + quad * 8;
            float4 a  = *(const float4*)(qrow + d0);
            float4 b4 = *(const float4*)(qrow + d0 + 4);
            float xs[8] = {a.x, a.y, a.z, a.w, b4.x, b4.y, b4.z, b4.w};
#pragma unroll
            for (int j2 = 0; j2 < 8; j2++)
                split2(xs[j2] * 0.125f, qh[s].u[j2], ql[s].u[j2]);
        }
    }

    // ---- stage 32-row x 64-dim fp32 tile -> hi/lo granule regions ----
    auto stage_tile = [&](const float* src, size_t rstride, u16* dhi, u16* dlo) {
        int r = tid >> 3, f = tid & 7;
        const float* p = src + (size_t)r * rstride + f * 8;
        float4 a  = *(const float4*)p;
        float4 b4 = *(const float4*)(p + 4);
        float xs[8] = {a.x, a.y, a.z, a.w, b4.x, b4.y, b4.z, b4.w};
        u32 hw[4], lw[4];
#pragma unroll
        for (int e = 0; e < 4; e++) {
            u16 h0, l0, h1, l1;
            split2(xs[2 * e], h0, l0);
            split2(xs[2 * e + 1], h1, l1);
            hw[e] = (u32)h0 | ((u32)h1 << 16);
            lw[e] = (u32)l0 | ((u32)l1 << 16);
        }
        int g = ((r >> 4) << 7) + ((r & 15) << 3) + ((f + 5 * r) & 7);
        *(uint4*)(dhi + g * 8) = make_uint4(hw[0], hw[1], hw[2], hw[3]);
        *(uint4*)(dlo + g * 8) = make_uint4(lw[0], lw[1], lw[2], lw[3]);
    };
    // thread covers rows {r0,r0+1} x dims {d0..d0+3}; one u32 per granule
    auto stage_V = [&](int j0) {
        int r0 = (tid & 15) * 2, d0 = (tid >> 4) * 4;
        const float* p0 = v + bh_off + (size_t)(j0 + r0) * DD + d0;
        float4 va = *(const float4*)p0;
        float4 vb = *(const float4*)(p0 + DD);
        float fa[4] = {va.x, va.y, va.z, va.w};
        float fb[4] = {vb.x, vb.y, vb.z, vb.w};
        int kq = r0 >> 3, wrd = (r0 >> 1) & 3;
        int ntd = d0 >> 4, nb = d0 & 15;
#pragma unroll
        for (int e = 0; e < 4; e++) {
            u16 ha, la, hb, lb;
            split2(fa[e], ha, la);
            split2(fb[e], hb, lb);
            int g = ntd * 80 + (nb + e) * 5 + kq;
            ((u32*)Vhi)[g * 4 + wrd] = (u32)ha | ((u32)hb << 16);
            ((u32*)Vlo)[g * 4 + wrd] = (u32)la | ((u32)lb << 16);
        }
    };
    auto read_frag = [&](const u16* reg, int nt, int s) -> bf16x8 {
        int g = (nt << 7) + (c << 3) + (((s << 2) + quad + 5 * c) & 7);
        return *(const bf16x8*)(reg + g * 8);
    };
    auto read_vfrag = [&](const u16* reg, int ntd) -> bf16x8 {
        int g = ntd * 80 + c * 5 + quad;
        return *(const bf16x8*)(reg + g * 8);
    };
    // Rel2 chunk (32 m-values) for this wave's 16 rows -> ring slot cidx&3
    auto produce_rel2 = [&](int cidx) {
        float* ringw = ringf + w * 2240 + (cidx & 3) * 560;
        int m0a = cidx * 32;
#pragma unroll
        for (int nt = 0; nt < 2; nt++) {
            f32x4 rc = {0.f, 0.f, 0.f, 0.f};
#pragma unroll
            for (int s = 0; s < 2; s++) {
                bf16x8 bh = read_frag(Rhi, nt, s);
                bf16x8 bl = read_frag(Rlo, nt, s);
                rc = __builtin_amdgcn_mfma_f32_16x16x32_bf16(qh[s].f, bh, rc, 0, 0, 0);
                rc = __builtin_amdgcn_mfma_f32_16x16x32_bf16(qh[s].f, bl, rc, 0, 0, 0);
                rc = __builtin_amdgcn_mfma_f32_16x16x32_bf16(ql[s].f, bh, rc, 0, 0, 0);
            }
            int mpos = nt * 16 + c;
            float rbv = rbrk[(size_t)h * (2 * TT) + m0a + mpos];
#pragma unroll
            for (int r = 0; r < 4; r++)
                ringw[(quad * 4 + r) * 35 + mpos] = rc[r] + rbv;
        }
    };

    const int k0c = (TT - i0 - 63) >> 5;   // (TT-i0-63) % 32 == 1

    // ---- prologue: rel2 chunks k0c, k0c+1 ----
    stage_tile(relk + ((size_t)(k0c * 32) * HH + h) * DK, (size_t)HH * DK, Rhi, Rlo);
    __syncthreads();
    produce_rel2(k0c);
    __syncthreads();
    stage_tile(relk + ((size_t)((k0c + 1) * 32) * HH + h) * DK, (size_t)HH * DK, Rhi, Rlo);
    __syncthreads();
    produce_rel2(k0c + 1);

    float m_run[4], l_run[4];
    f32x4 o[4];
#pragma unroll
    for (int r = 0; r < 4; r++) { m_run[r] = -INFINITY; l_run[r] = 0.f; }
#pragma unroll
    for (int nt = 0; nt < 4; nt++) o[nt] = (f32x4){0.f, 0.f, 0.f, 0.f};

    for (int jt = 0; jt < TT / 32; jt++) {
        const int j0 = jt * 32;
        __syncthreads();   // prior iteration's K/V reads + produce's R reads done
        stage_tile(k + bh_off + (size_t)j0 * DD, (size_t)DD, Khi, Klo);
        stage_V(j0);
        stage_tile(relk + ((size_t)((k0c + jt + 2) * 32) * HH + h) * DK,
                   (size_t)HH * DK, Rhi, Rlo);
        __syncthreads();
        produce_rel2(k0c + jt + 2);

        // ---- S = QK (MFMA) + rel gather + cbk ----
        const int mb0 = TT - i0 - 16 * w + j0;
        float sv[2][4];
#pragma unroll
        for (int nt = 0; nt < 2; nt++) {
            f32x4 sc = {0.f, 0.f, 0.f, 0.f};
#pragma unroll
            for (int s = 0; s < 2; s++) {
                bf16x8 bh = read_frag(Khi, nt, s);
                bf16x8 bl = read_frag(Klo, nt, s);
                sc = __builtin_amdgcn_mfma_f32_16x16x32_bf16(qh[s].f, bh, sc, 0, 0, 0);
                sc = __builtin_amdgcn_mfma_f32_16x16x32_bf16(qh[s].f, bl, sc, 0, 0, 0);
                sc = __builtin_amdgcn_mfma_f32_16x16x32_bf16(ql[s].f, bh, sc, 0, 0, 0);
            }
            int j_abs = j0 + nt * 16 + c;
            float cbv = cbk[((size_t)h * BB + b) * TT + j_abs];
            int mc = mb0 + nt * 16 + c;
#pragma unroll
            for (int r = 0; r < 4; r++) {
                int row16 = quad * 4 + r;
                int m_abs = mc - row16;
                float rel = ringf[w * 2240 + ((m_abs >> 5) & 3) * 560
                                  + row16 * 35 + (m_abs & 31)];
                sv[nt][r] = sc[r] + rel + cbv;
            }
        }

        // ---- online softmax (16 lanes per row) + P write (packed u32) ----
#pragma unroll
        for (int r = 0; r < 4; r++) {
            float tm = fmaxf(sv[0][r], sv[1][r]);
#pragma unroll
            for (int off = 1; off < 16; off <<= 1) tm = fmaxf(tm, __shfl_xor(tm, off));
            float mnew = fmaxf(m_run[r], tm);
            float al = __expf(m_run[r] - mnew);
            float p0 = __expf(sv[0][r] - mnew);
            float p1 = __expf(sv[1][r] - mnew);
            float ps = p0 + p1;
#pragma unroll
            for (int off = 1; off < 16; off <<= 1) ps += __shfl_xor(ps, off);
            l_run[r] = l_run[r] * al + ps;
            m_run[r] = mnew;
#pragma unroll
            for (int nt = 0; nt < 4; nt++) o[nt][r] *= al;
            u32* pb = Pbuf + w * 544 + (quad * 4 + r) * 34;
            pb[c]      = split_pack(p0);
            pb[16 + c] = split_pack(p1);
        }

        // ---- O += P @ V (hi/lo) ----
        frag_u ph, pl;
        {
            const u32* pb = Pbuf + w * 544 + c * 34 + quad * 8;
            uint2 r0 = *(const uint2*)(pb);
            uint2 r1 = *(const uint2*)(pb + 2);
            uint2 r2 = *(const uint2*)(pb + 4);
            uint2 r3 = *(const uint2*)(pb + 6);
            u32 pk[8] = {r0.x, r0.y, r1.x, r1.y, r2.x, r2.y, r3.x, r3.y};
#pragma unroll
            for (int j2 = 0; j2 < 8; j2++) {
                ph.u[j2] = (u16)(pk[j2] >> 16);
                pl.u[j2] = (u16)(pk[j2] & 0xffffu);
            }
        }
#pragma unroll
        for (int ntd = 0; ntd < 4; ntd++) {
            bf16x8 vh = read_vfrag(Vhi, ntd);
            bf16x8 vl = read_vfrag(Vlo, ntd);
            o[ntd] = __builtin_amdgcn_mfma_f32_16x16x32_bf16(ph.f, vh, o[ntd], 0, 0, 0);
            o[ntd] = __builtin_amdgcn_mfma_f32_16x16x32_bf16(ph.f, vl, o[ntd], 0, 0, 0);
            o[ntd] = __builtin_amdgcn_mfma_f32_16x16x32_bf16(pl.f, vh, o[ntd], 0, 0, 0);
        }
    }

    // ---- epilogue: normalize, store [B,T,H*Dk] ----
#pragma unroll
    for (int nt = 0; nt < 4; nt++) {
#pragma unroll
        for (int r = 0; r < 4; r++) {
            int row16 = quad * 4 + r;
            int i_abs = i0 + 16 * w + row16;
            attn_out[((size_t)b * TT + i_abs) * DD + h * DK + nt * 16 + c] =
                o[nt][r] / l_run[r];
        }
    }
}

// ---------------------------------------------------------------------------
extern "C" void kernel_launch(void* const* d_in, const int* in_sizes, int n_in,
                              void* d_out, int out_size, void* d_ws, size_t ws_size,
                              hipStream_t stream) {
    const float* query  = (const float*)d_in[0];
    const float* key_in = (const float*)d_in[1];
    const float* value  = (const float*)d_in[2];
    const float* Wq = (const float*)d_in[3];
    const float* bq = (const float*)d_in[4];
    const float* Wk = (const float*)d_in[5];
    const float* bk = (const float*)d_in[6];
    const float* Wv = (const float*)d_in[7];
    const float* bv = (const float*)d_in[8];
    const float* Wr = (const float*)d_in[9];
    const float* cb = (const float*)d_in[10];
    const float* rb = (const float*)d_in[11];
    const float* Wo = (const float*)d_in[12];
    const float* bo = (const float*)d_in[13];
    float* out = (float*)d_out;

    float* ws = (float*)d_ws;
    const size_t SL = (size_t)MM * DD;
    float* qb    = ws;
    float* kb    = ws + SL;
    float* vb    = ws + 2 * SL;
    float* relk  = ws + 3 * SL;
    float* attnv = ws + 4 * SL;
    float* pe    = attnv;            // pe consumed before attnv written
    float* cbk   = ws + 5 * SL;
    float* rbrk  = cbk + BB * TT * HH;

    const dim3 gemm_grid(DD / 64, MM / 64);

    pe_kernel<<<(2 * TT * DD) / 256, 256, 0, stream>>>(pe);
    gemm_bias_kernel<<<gemm_grid, 256, 0, stream>>>(pe, Wr, nullptr, relk, MM, DD, DD);
    gemm_bias_kernel<<<gemm_grid, 256, 0, stream>>>(query,  Wq, bq, qb, MM, DD, DD);
    gemm_bias_kernel<<<gemm_grid, 256, 0, stream>>>(key_in, Wk, bk, kb, MM, DD, DD);
    gemm_bias_kernel<<<gemm_grid, 256, 0, stream>>>(value,  Wv, bv, vb, MM, DD, DD);
    bias_dots_kernel<<<(BB * TT * HH + 2 * TT * HH) / 256, 256, 0, stream>>>(
        kb, relk, cb, rb, cbk, rbrk);
    attn_mfma_kernel<<<BB * HH * (TT / 64), 256, 0, stream>>>(
        qb, kb, vb, relk, cbk, rbrk, attnv);
    gemm_bias_kernel<<<gemm_grid, 256, 0, stream>>>(attnv, Wo, bo, out, MM, DD, DD);
}